// Round 4
// baseline (4483.295 us; speedup 1.0000x reference)
//
#include <hip/hip_runtime.h>
#include <hip/hip_bf16.h>

typedef __bf16 bf16x8 __attribute__((ext_vector_type(8)));
typedef float floatx4 __attribute__((ext_vector_type(4)));

#define DEV __device__ __forceinline__

DEV float gelu_f(float x) {
    return 0.5f * x * (1.0f + erff(x * 0.70710678118654752f));
}

DEV void block_reduce2(float& a, float& b, float* s) {
    #pragma unroll
    for (int o = 32; o > 0; o >>= 1) {
        a += __shfl_down(a, o, 64);
        b += __shfl_down(b, o, 64);
    }
    __syncthreads();
    int wv = threadIdx.x >> 6;
    if ((threadIdx.x & 63) == 0) { s[wv * 2] = a; s[wv * 2 + 1] = b; }
    __syncthreads();
    int nw = blockDim.x >> 6;
    float ra = 0.f, rb = 0.f;
    for (int i = 0; i < nw; ++i) { ra += s[i * 2]; rb += s[i * 2 + 1]; }
    a = ra; b = rb;
}

// ---------------------------------------------------------------- lb: softmax over depth, cumsum, minus first
__global__ __launch_bounds__(256) void compute_lb(const float* __restrict__ lbin, float* __restrict__ lbout) {
    int d = blockIdx.x * 256 + threadIdx.x;
    if (d >= 768) return;
    float v[8];
    float mx = -1e30f;
    #pragma unroll
    for (int i = 0; i < 8; ++i) { v[i] = lbin[i * 768 + d]; mx = fmaxf(mx, v[i]); }
    float s = 0.f;
    #pragma unroll
    for (int i = 0; i < 8; ++i) { v[i] = expf(v[i] - mx); s += v[i]; }
    float inv = 1.f / s;
    float first = v[0] * inv;
    float cum = 0.f;
    #pragma unroll
    for (int i = 0; i < 8; ++i) { cum += v[i] * inv; lbout[i * 768 + d] = cum - first; }
}

// ---------------------------------------------------------------- x init: cls row = cls+pos[0]; token rows = spt_b+pos[1+p]
__global__ __launch_bounds__(256) void init_tokens(const float* __restrict__ cls, const float* __restrict__ pos,
                                                   const float* __restrict__ bias, float* __restrict__ x) {
    int i = blockIdx.x * 256 + threadIdx.x;       // 16*257*768 = 3157248
    if (i >= 16 * 257 * 768) return;
    int d = i % 768;
    int row = i / 768;                             // b*257 + t
    int t = row % 257;
    float v;
    if (t == 0) v = cls[d] + pos[d];
    else        v = bias[d] + pos[(size_t)t * 768 + d];
    x[(size_t)row * 768 + d] = v;
}

// ---------------------------------------------------------------- patch gather + layernorm -> bf16 [4096 x 3840]
__global__ __launch_bounds__(256) void patch_ln(const float* __restrict__ img, const float* __restrict__ g,
                                                const float* __restrict__ bt, __hip_bfloat16* __restrict__ out) {
    int pm = blockIdx.x;              // 0..4095   = b*256 + (ph*16+pw)
    int b = pm >> 8, pp = pm & 255;
    int ph = pp >> 4, pw = pp & 15;
    __shared__ float pv[3840];
    __shared__ float sbuf[8];
    float s = 0.f, ss = 0.f;
    #pragma unroll
    for (int i = 0; i < 15; ++i) {
        int f = threadIdx.x + i * 256;
        int pi = f / 15, cc = f % 15;
        int ip = pi >> 4, jp = pi & 15;
        int g5 = cc / 3, ch = cc % 3;
        int sh = (g5 == 3) - (g5 == 4);       // groups: 0:(0,0) 1:(0,1) 2:(0,-1) 3:(1,0) 4:(-1,0)
        int sw = (g5 == 1) - (g5 == 2);
        int y = ph * 16 + ip - sh;
        int x = pw * 16 + jp - sw;
        float val = 0.f;
        if ((unsigned)y < 256u && (unsigned)x < 256u)
            val = img[(((size_t)b * 3 + ch) * 256 + y) * 256 + x];
        pv[f] = val; s += val; ss += val * val;
    }
    block_reduce2(s, ss, sbuf);
    float mean = s * (1.f / 3840.f);
    float var  = ss * (1.f / 3840.f) - mean * mean;
    float inv  = rsqrtf(var + 1e-5f);
    #pragma unroll
    for (int i = 0; i < 15; ++i) {
        int f = threadIdx.x + i * 256;
        out[(size_t)pm * 3840 + f] = __float2bfloat16((pv[f] - mean) * inv * g[f] + bt[f]);
    }
}

// ---------------------------------------------------------------- fp32 [K,N] -> bf16 [N,K] tiled transpose-cast
__global__ __launch_bounds__(256) void transpose_cast(const float* __restrict__ W, __hip_bfloat16* __restrict__ Wt,
                                                      int K, int N) {
    __shared__ float tile[32][33];
    int k0 = blockIdx.x * 32, n0 = blockIdx.y * 32;
    int tx = threadIdx.x & 31, ty = threadIdx.x >> 5;   // ty 0..7
    #pragma unroll
    for (int i = 0; i < 4; ++i) {
        int k = ty + i * 8;
        tile[k][tx] = W[(size_t)(k0 + k) * N + n0 + tx];
    }
    __syncthreads();
    #pragma unroll
    for (int i = 0; i < 4; ++i) {
        int n = ty + i * 8;
        Wt[(size_t)(n0 + n) * K + k0 + tx] = __float2bfloat16(tile[tx][n]);
    }
}

// ---------------------------------------------------------------- rmsnorm fp32 -> bf16, row = 768
__global__ __launch_bounds__(256) void rmsnorm_kernel(const float* __restrict__ x, __hip_bfloat16* __restrict__ out) {
    int row = blockIdx.x;
    const float* xr = x + (size_t)row * 768;
    __shared__ float sbuf[8];
    float v[3];
    float ss = 0.f, d0 = 0.f;
    #pragma unroll
    for (int i = 0; i < 3; ++i) { v[i] = xr[threadIdx.x + i * 256]; ss += v[i] * v[i]; }
    block_reduce2(ss, d0, sbuf);
    float scale = rsqrtf(ss * (1.f / 768.f) + 1e-6f);
    #pragma unroll
    for (int i = 0; i < 3; ++i)
        out[(size_t)row * 768 + threadIdx.x + i * 256] = __float2bfloat16(v[i] * scale);
}

// ---------------------------------------------------------------- hgru2 scan over BATCH axis (N=16), per (t,h), bf16 feat
__global__ __launch_bounds__(256) void hgru_scan(const __hip_bfloat162* __restrict__ feat,
                                                 __hip_bfloat16* __restrict__ o) {
    int idx = blockIdx.x * 256 + threadIdx.x;
    if (idx >= 257 * 384) return;
    int t = idx / 384, h = idx % 384;
    float S00 = 0.f, S01 = 0.f, S10 = 0.f, S11 = 0.f;
    for (int n = 0; n < 16; ++n) {
        size_t b2 = ((size_t)n * 257 + t) * 1152;    // row base in bf16x2 units
        __hip_bfloat162 V = feat[b2 + h];
        __hip_bfloat162 Q = feat[b2 + 384 + h];
        __hip_bfloat162 L = feat[b2 + 768 + h];
        float v0 = __bfloat162float(V.x), v1 = __bfloat162float(V.y);
        float q0 = __bfloat162float(Q.x), q1 = __bfloat162float(Q.y);
        float l0 = __bfloat162float(L.x), l1 = __bfloat162float(L.y);
        float k0 = 1.f - l0, k1 = 1.f - l1;
        S00 = l0 * S00 + k0 * v0; S01 = l0 * S01 + k0 * v1;
        S10 = l1 * S10 + k1 * v0; S11 = l1 * S11 + k1 * v1;
        float o0 = q0 * S00 + q1 * S10;
        float o1 = q0 * S01 + q1 * S11;
        size_t ob = ((size_t)n * 257 + t) * 768 + h * 2;
        o[ob]     = __float2bfloat16(o0);
        o[ob + 1] = __float2bfloat16(o1);
    }
}

// ---------------------------------------------------------------- final: rmsnorm + layernorm + head GEMM (tiny)
__global__ __launch_bounds__(256) void head_kernel(const float* __restrict__ x, const float* __restrict__ g,
                                                   const float* __restrict__ be, const float* __restrict__ hw,
                                                   const float* __restrict__ hb, float* __restrict__ out) {
    int b = blockIdx.x;
    const float* xr = x + (size_t)b * 257 * 768;
    __shared__ float z[768];
    __shared__ float sbuf[8];
    float v[3];
    float ss = 0.f, d0 = 0.f;
    #pragma unroll
    for (int i = 0; i < 3; ++i) { v[i] = xr[threadIdx.x + i * 256]; ss += v[i] * v[i]; }
    block_reduce2(ss, d0, sbuf);
    float rs = rsqrtf(ss * (1.f / 768.f) + 1e-6f);
    float s = 0.f, s2 = 0.f;
    #pragma unroll
    for (int i = 0; i < 3; ++i) { float y = v[i] * rs; s += y; s2 += y * y; }
    block_reduce2(s, s2, sbuf);
    float mean = s * (1.f / 768.f);
    float var  = s2 * (1.f / 768.f) - mean * mean;
    float inv  = rsqrtf(var + 1e-5f);
    #pragma unroll
    for (int i = 0; i < 3; ++i) {
        int d = threadIdx.x + i * 256;
        z[d] = (v[i] * rs - mean) * inv * g[d] + be[d];
    }
    __syncthreads();
    int j = blockIdx.y * 256 + threadIdx.x;
    if (j < 1000) {
        float acc = hb[j];
        for (int d = 0; d < 768; ++d) acc += z[d] * hw[d * 1000 + j];
        out[b * 1000 + j] = acc;
    }
}

// ---------------------------------------------------------------- bf16 MFMA GEMM: C[M,N] = A[M,K] @ Bt[N,K]^T
// 128xNT tile (NT=128|64), BK=32, 4 waves (2x2), 4xNF 16x16x32 frags/wave.
// Register-prefetch pipeline with ALL indices compile-time (round-3's runtime-indexed
// reg arrays spilled to scratch: 327 MB WRITE_SIZE). Two Stage structs (scalar int4
// members -> SROA to VGPRs), K-loop unrolled x2 so stage/buffer parity is static.
// Requires nk even (all call sites satisfy this).
// Per iter: gload tile k+2 -> regs (no wait), ds_write tile k+1 regs->LDS (vmcnt wait
// lands here, one full compute+barrier after issue), ds_read frags + MFMA tile k,
// ONE barrier draining only LDS ops.
// LDS XOR-swizzled (16B chunk ^= (row>>1)&3): 0 bank conflicts (measured r3).
// Split-K via blockIdx.z; linear epilogues accumulate with fp32 atomicAdd.
// EPI: 0=patch-embed partial (+= into pre-initialized x rows, row remap)
//      1=hgru feat (gelu/gelu/lambda) -> bf16  2=residual partial (+=)
//      3=bias+gelu->bf16  4=bias+residual partial (+=)
template<int EPI, int SPLITK, int NT>
__global__ __launch_bounds__(256) void gemm_bt(
        const __hip_bfloat16* __restrict__ A, const __hip_bfloat16* __restrict__ Bt,
        int N, int Ktot, int Mvalid,
        float* __restrict__ outf, __hip_bfloat16* __restrict__ outb,
        const float* __restrict__ bias, const float* __restrict__ aux) {
    constexpr int NF = NT / 32;           // n-frags per wave
    constexpr int BJ = NT / 64;           // B staging loads per thread (1 or 2)
    __shared__ alignas(16) __hip_bfloat16 Als[2][128 * 32];
    __shared__ alignas(16) __hip_bfloat16 Bls[2][NT * 32];
    const int tid  = threadIdx.x;
    const int lane = tid & 63;
    const int wv   = tid >> 6;
    const int m0 = blockIdx.y * 128;
    const int n0 = blockIdx.x * NT;
    const int kLen  = Ktot / SPLITK;
    const int kBase = blockIdx.z * kLen;
    const int wm = wv & 1, wn = wv >> 1;
    const int fr = lane & 15;
    const int fq = lane >> 4;
    const int sr = tid >> 2;              // staging row 0..63 (+64)
    const int sc = tid & 3;               // staging 16B chunk 0..3

    floatx4 acc[4][NF];
    #pragma unroll
    for (int mi = 0; mi < 4; ++mi)
        #pragma unroll
        for (int ni = 0; ni < NF; ++ni)
            acc[mi][ni] = (floatx4){0.f, 0.f, 0.f, 0.f};

    struct Stage { int4 a0, a1, b0, b1; };
    Stage s0, s1;

    auto gload = [&](int kt, Stage& st) {
        st.a0 = *(const int4*)(A + (size_t)(m0 + sr) * Ktot + kBase + kt + sc * 8);
        st.a1 = *(const int4*)(A + (size_t)(m0 + sr + 64) * Ktot + kBase + kt + sc * 8);
        st.b0 = *(const int4*)(Bt + (size_t)(n0 + sr) * Ktot + kBase + kt + sc * 8);
        if (BJ > 1)
            st.b1 = *(const int4*)(Bt + (size_t)(n0 + sr + 64) * Ktot + kBase + kt + sc * 8);
    };
    auto swz = [&](int row, int chunk) -> int {   // byte offset inside a tile
        return row * 64 + ((chunk ^ ((row >> 1) & 3)) * 16);
    };
    auto swrite = [&](int buf, const Stage& st) {
        *(int4*)((char*)&Als[buf][0] + swz(sr, sc))      = st.a0;
        *(int4*)((char*)&Als[buf][0] + swz(sr + 64, sc)) = st.a1;
        *(int4*)((char*)&Bls[buf][0] + swz(sr, sc))      = st.b0;
        if (BJ > 1)
            *(int4*)((char*)&Bls[buf][0] + swz(sr + 64, sc)) = st.b1;
    };
    auto compute = [&](int buf) {
        bf16x8 af[4], bfv[NF];
        #pragma unroll
        for (int mi = 0; mi < 4; ++mi)
            af[mi] = *(const bf16x8*)((const char*)&Als[buf][0] + swz(wm * 64 + mi * 16 + fr, fq));
        #pragma unroll
        for (int ni = 0; ni < NF; ++ni)
            bfv[ni] = *(const bf16x8*)((const char*)&Bls[buf][0] + swz(wn * (NT / 2) + ni * 16 + fr, fq));
        #pragma unroll
        for (int mi = 0; mi < 4; ++mi)
            #pragma unroll
            for (int ni = 0; ni < NF; ++ni)
                acc[mi][ni] = __builtin_amdgcn_mfma_f32_16x16x32_bf16(af[mi], bfv[ni], acc[mi][ni], 0, 0, 0);
    };

    const int nk = kLen / 32;             // even at every call site
    gload(0, s0);
    gload(32, s1);
    swrite(0, s0);
    __syncthreads();

    for (int i = 0; i < nk; i += 2) {
        // even iter: compute buf0
        if (i + 2 < nk) gload((i + 2) * 32, s0);
        swrite(1, s1);                    // tile i+1 -> buf1 (prev buf1 reads done at last barrier)
        compute(0);
        __syncthreads();
        // odd iter: compute buf1
        if (i + 3 < nk) gload((i + 3) * 32, s1);
        if (i + 2 < nk) swrite(0, s0);    // tile i+2 -> buf0
        compute(1);
        if (i + 2 < nk) __syncthreads();
    }

    // C/D layout: col = lane&15, row = (lane>>4)*4 + reg  [m89/m91-verified]
    const int cr0 = wm * 64 + fq * 4;
    const int cc0 = wn * (NT / 2) + fr;
    #pragma unroll
    for (int mi = 0; mi < 4; ++mi) {
        #pragma unroll
        for (int r = 0; r < 4; ++r) {
            int gm = m0 + cr0 + mi * 16 + r;
            if (gm >= Mvalid) continue;
            #pragma unroll
            for (int ni = 0; ni < NF; ++ni) {
                int gn = n0 + cc0 + ni * 16;
                float v = acc[mi][ni][r];
                if (EPI == 0) {
                    int b = gm >> 8, p = gm & 255;
                    size_t orow = (size_t)b * 257 + 1 + p;
                    atomicAdd(&outf[orow * 768 + gn], v);
                } else if (EPI == 1) {
                    float res;
                    if (gn < 1536) {
                        res = gelu_f(v);
                    } else {
                        float l = aux[gn - 1536];
                        res = l + (1.f - l) / (1.f + expf(-v));
                    }
                    outb[(size_t)gm * N + gn] = __float2bfloat16(res);
                } else if (EPI == 2) {
                    if (SPLITK > 1) atomicAdd(&outf[(size_t)gm * N + gn], v);
                    else            outf[(size_t)gm * N + gn] += v;
                } else if (EPI == 3) {
                    outb[(size_t)gm * N + gn] = __float2bfloat16(gelu_f(v + bias[gn]));
                } else if (EPI == 4) {
                    float add = v + (blockIdx.z == 0 ? bias[gn] : 0.f);
                    if (SPLITK > 1) atomicAdd(&outf[(size_t)gm * N + gn], add);
                    else            outf[(size_t)gm * N + gn] += add;
                }
            }
        }
    }
}

// ----------------------------------------------------------------
extern "C" void kernel_launch(void* const* d_in, const int* in_sizes, int n_in,
                              void* d_out, int out_size, void* d_ws, size_t ws_size,
                              hipStream_t stream) {
    const float* img        = (const float*)d_in[0];
    const float* spt_ln_g   = (const float*)d_in[1];
    const float* spt_ln_b   = (const float*)d_in[2];
    const float* spt_w      = (const float*)d_in[3];
    const float* spt_b      = (const float*)d_in[4];
    const float* pos_emb    = (const float*)d_in[5];
    const float* cls_token  = (const float*)d_in[6];
    const float* lower_bnds = (const float*)d_in[7];
    const float* in_proj_w  = (const float*)d_in[8];
    const float* out_proj_w = (const float*)d_in[9];
    const float* ff_w1      = (const float*)d_in[10];
    const float* ff_b1      = (const float*)d_in[11];
    const float* ff_w2      = (const float*)d_in[12];
    const float* ff_b2      = (const float*)d_in[13];
    const float* head_ln_g  = (const float*)d_in[14];
    const float* head_ln_b  = (const float*)d_in[15];
    const float* head_w     = (const float*)d_in[16];
    const float* head_b     = (const float*)d_in[17];
    float* out = (float*)d_out;

    // ---- workspace bump allocator (256B aligned). Total ~120 MB.
    char* wp = (char*)d_ws;
    auto alloc = [&](size_t bytes) -> void* {
        void* p = (void*)wp;
        wp += (bytes + 255) & ~(size_t)255;
        return p;
    };
    float*          lbbuf   = (float*)         alloc(8 * 768 * 4);
    __hip_bfloat16* patches = (__hip_bfloat16*)alloc((size_t)4096 * 3840 * 2);
    __hip_bfloat16* spt_wt  = (__hip_bfloat16*)alloc((size_t)768 * 3840 * 2);
    float*          xbuf    = (float*)         alloc((size_t)4112 * 768 * 4);
    __hip_bfloat16* normbuf = (__hip_bfloat16*)alloc((size_t)4224 * 768 * 2);   // padded M
    __hip_bfloat16* featbuf = (__hip_bfloat16*)alloc((size_t)4112 * 2304 * 2);  // bf16
    __hip_bfloat16* obuf    = (__hip_bfloat16*)alloc((size_t)4224 * 768 * 2);   // padded M
    __hip_bfloat16* midbuf  = (__hip_bfloat16*)alloc((size_t)4224 * 3072 * 2);  // padded M
    __hip_bfloat16* w_in_t  = (__hip_bfloat16*)alloc((size_t)2304 * 768 * 2);
    __hip_bfloat16* w_out_t = (__hip_bfloat16*)alloc((size_t)768 * 768 * 2);
    __hip_bfloat16* w1_t    = (__hip_bfloat16*)alloc((size_t)3072 * 768 * 2);
    __hip_bfloat16* w2_t    = (__hip_bfloat16*)alloc((size_t)768 * 3072 * 2);
    (void)in_sizes; (void)n_in; (void)out_size; (void)ws_size;

    // ---- prologue
    compute_lb<<<3, 256, 0, stream>>>(lower_bnds, lbbuf);
    init_tokens<<<(16 * 257 * 768 + 255) / 256, 256, 0, stream>>>(cls_token, pos_emb, spt_b, xbuf);
    patch_ln<<<4096, 256, 0, stream>>>(img, spt_ln_g, spt_ln_b, patches);
    transpose_cast<<<dim3(3840 / 32, 768 / 32), 256, 0, stream>>>(spt_w, spt_wt, 3840, 768);
    // x rows (b*257+1+p) += LN(patches) @ spt_w   (bias+pos already in xbuf), split-K=4, nk=30
    gemm_bt<0, 4, 128><<<dim3(6, 32, 4), 256, 0, stream>>>(patches, spt_wt, 768, 3840, 4096,
                                                           xbuf, nullptr, nullptr, nullptr);

    // ---- layers
    for (int i = 0; i < 8; ++i) {
        rmsnorm_kernel<<<4112, 256, 0, stream>>>(xbuf, normbuf);
        transpose_cast<<<dim3(24, 72), 256, 0, stream>>>(in_proj_w + (size_t)i * 768 * 2304, w_in_t, 768, 2304);
        gemm_bt<1, 1, 128><<<dim3(18, 33, 1), 256, 0, stream>>>(normbuf, w_in_t, 2304, 768, 4112,
                                                                nullptr, featbuf, nullptr, lbbuf + i * 768);  // nk=24
        hgru_scan<<<386, 256, 0, stream>>>((const __hip_bfloat162*)featbuf, obuf);
        transpose_cast<<<dim3(24, 24), 256, 0, stream>>>(out_proj_w + (size_t)i * 768 * 768, w_out_t, 768, 768);
        gemm_bt<2, 2, 64><<<dim3(12, 33, 2), 256, 0, stream>>>(obuf, w_out_t, 768, 768, 4112,
                                                               xbuf, nullptr, nullptr, nullptr);             // nk=12
        rmsnorm_kernel<<<4112, 256, 0, stream>>>(xbuf, normbuf);
        transpose_cast<<<dim3(24, 96), 256, 0, stream>>>(ff_w1 + (size_t)i * 768 * 3072, w1_t, 768, 3072);
        gemm_bt<3, 1, 128><<<dim3(24, 33, 1), 256, 0, stream>>>(normbuf, w1_t, 3072, 768, 4112,
                                                                nullptr, midbuf, ff_b1 + i * 3072, nullptr); // nk=24
        transpose_cast<<<dim3(96, 24), 256, 0, stream>>>(ff_w2 + (size_t)i * 3072 * 768, w2_t, 3072, 768);
        gemm_bt<4, 4, 128><<<dim3(6, 33, 4), 256, 0, stream>>>(midbuf, w2_t, 768, 3072, 4112,
                                                               xbuf, nullptr, ff_b2 + i * 768, nullptr);     // nk=24
    }

    // ---- head
    head_kernel<<<dim3(16, 4), 256, 0, stream>>>(xbuf, head_ln_g, head_ln_b, head_w, head_b, out);
}

// Round 5
// 4349.266 us; speedup vs baseline: 1.0308x; 1.0308x over previous
//
#include <hip/hip_runtime.h>
#include <hip/hip_bf16.h>

typedef __bf16 bf16x8 __attribute__((ext_vector_type(8)));
typedef float floatx4 __attribute__((ext_vector_type(4)));

#define DEV __device__ __forceinline__

DEV float gelu_f(float x) {
    return 0.5f * x * (1.0f + erff(x * 0.70710678118654752f));
}

DEV void block_reduce2(float& a, float& b, float* s) {
    #pragma unroll
    for (int o = 32; o > 0; o >>= 1) {
        a += __shfl_down(a, o, 64);
        b += __shfl_down(b, o, 64);
    }
    __syncthreads();
    int wv = threadIdx.x >> 6;
    if ((threadIdx.x & 63) == 0) { s[wv * 2] = a; s[wv * 2 + 1] = b; }
    __syncthreads();
    int nw = blockDim.x >> 6;
    float ra = 0.f, rb = 0.f;
    for (int i = 0; i < nw; ++i) { ra += s[i * 2]; rb += s[i * 2 + 1]; }
    a = ra; b = rb;
}

// ---------------------------------------------------------------- lb: softmax over depth, cumsum, minus first
__global__ __launch_bounds__(256) void compute_lb(const float* __restrict__ lbin, float* __restrict__ lbout) {
    int d = blockIdx.x * 256 + threadIdx.x;
    if (d >= 768) return;
    float v[8];
    float mx = -1e30f;
    #pragma unroll
    for (int i = 0; i < 8; ++i) { v[i] = lbin[i * 768 + d]; mx = fmaxf(mx, v[i]); }
    float s = 0.f;
    #pragma unroll
    for (int i = 0; i < 8; ++i) { v[i] = expf(v[i] - mx); s += v[i]; }
    float inv = 1.f / s;
    float first = v[0] * inv;
    float cum = 0.f;
    #pragma unroll
    for (int i = 0; i < 8; ++i) { cum += v[i] * inv; lbout[i * 768 + d] = cum - first; }
}

// ---------------------------------------------------------------- x init: cls row = cls+pos[0]; token rows = spt_b+pos[1+p]
__global__ __launch_bounds__(256) void init_tokens(const float* __restrict__ cls, const float* __restrict__ pos,
                                                   const float* __restrict__ bias, float* __restrict__ x) {
    int i = blockIdx.x * 256 + threadIdx.x;       // 16*257*768 = 3157248
    if (i >= 16 * 257 * 768) return;
    int d = i % 768;
    int row = i / 768;                             // b*257 + t
    int t = row % 257;
    float v;
    if (t == 0) v = cls[d] + pos[d];
    else        v = bias[d] + pos[(size_t)t * 768 + d];
    x[(size_t)row * 768 + d] = v;
}

// ---------------------------------------------------------------- patch gather + layernorm -> bf16 [4096 x 3840]
__global__ __launch_bounds__(256) void patch_ln(const float* __restrict__ img, const float* __restrict__ g,
                                                const float* __restrict__ bt, __hip_bfloat16* __restrict__ out) {
    int pm = blockIdx.x;              // 0..4095   = b*256 + (ph*16+pw)
    int b = pm >> 8, pp = pm & 255;
    int ph = pp >> 4, pw = pp & 15;
    __shared__ float pv[3840];
    __shared__ float sbuf[8];
    float s = 0.f, ss = 0.f;
    #pragma unroll
    for (int i = 0; i < 15; ++i) {
        int f = threadIdx.x + i * 256;
        int pi = f / 15, cc = f % 15;
        int ip = pi >> 4, jp = pi & 15;
        int g5 = cc / 3, ch = cc % 3;
        int sh = (g5 == 3) - (g5 == 4);       // groups: 0:(0,0) 1:(0,1) 2:(0,-1) 3:(1,0) 4:(-1,0)
        int sw = (g5 == 1) - (g5 == 2);
        int y = ph * 16 + ip - sh;
        int x = pw * 16 + jp - sw;
        float val = 0.f;
        if ((unsigned)y < 256u && (unsigned)x < 256u)
            val = img[(((size_t)b * 3 + ch) * 256 + y) * 256 + x];
        pv[f] = val; s += val; ss += val * val;
    }
    block_reduce2(s, ss, sbuf);
    float mean = s * (1.f / 3840.f);
    float var  = ss * (1.f / 3840.f) - mean * mean;
    float inv  = rsqrtf(var + 1e-5f);
    #pragma unroll
    for (int i = 0; i < 15; ++i) {
        int f = threadIdx.x + i * 256;
        out[(size_t)pm * 3840 + f] = __float2bfloat16((pv[f] - mean) * inv * g[f] + bt[f]);
    }
}

// ---------------------------------------------------------------- fp32 [K,N] -> bf16 [N,K] tiled transpose-cast
__global__ __launch_bounds__(256) void transpose_cast(const float* __restrict__ W, __hip_bfloat16* __restrict__ Wt,
                                                      int K, int N) {
    __shared__ float tile[32][33];
    int k0 = blockIdx.x * 32, n0 = blockIdx.y * 32;
    int tx = threadIdx.x & 31, ty = threadIdx.x >> 5;   // ty 0..7
    #pragma unroll
    for (int i = 0; i < 4; ++i) {
        int k = ty + i * 8;
        tile[k][tx] = W[(size_t)(k0 + k) * N + n0 + tx];
    }
    __syncthreads();
    #pragma unroll
    for (int i = 0; i < 4; ++i) {
        int n = ty + i * 8;
        Wt[(size_t)(n0 + n) * K + k0 + tx] = __float2bfloat16(tile[tx][n]);
    }
}

// ---------------------------------------------------------------- rmsnorm fp32 -> bf16, row = 768
__global__ __launch_bounds__(256) void rmsnorm_kernel(const float* __restrict__ x, __hip_bfloat16* __restrict__ out) {
    int row = blockIdx.x;
    const float* xr = x + (size_t)row * 768;
    __shared__ float sbuf[8];
    float v[3];
    float ss = 0.f, d0 = 0.f;
    #pragma unroll
    for (int i = 0; i < 3; ++i) { v[i] = xr[threadIdx.x + i * 256]; ss += v[i] * v[i]; }
    block_reduce2(ss, d0, sbuf);
    float scale = rsqrtf(ss * (1.f / 768.f) + 1e-6f);
    #pragma unroll
    for (int i = 0; i < 3; ++i)
        out[(size_t)row * 768 + threadIdx.x + i * 256] = __float2bfloat16(v[i] * scale);
}

// ---------------------------------------------------------------- hgru2 scan over BATCH axis (N=16), per (t,h), bf16 feat
__global__ __launch_bounds__(256) void hgru_scan(const __hip_bfloat162* __restrict__ feat,
                                                 __hip_bfloat16* __restrict__ o) {
    int idx = blockIdx.x * 256 + threadIdx.x;
    if (idx >= 257 * 384) return;
    int t = idx / 384, h = idx % 384;
    float S00 = 0.f, S01 = 0.f, S10 = 0.f, S11 = 0.f;
    for (int n = 0; n < 16; ++n) {
        size_t b2 = ((size_t)n * 257 + t) * 1152;    // row base in bf16x2 units
        __hip_bfloat162 V = feat[b2 + h];
        __hip_bfloat162 Q = feat[b2 + 384 + h];
        __hip_bfloat162 L = feat[b2 + 768 + h];
        float v0 = __bfloat162float(V.x), v1 = __bfloat162float(V.y);
        float q0 = __bfloat162float(Q.x), q1 = __bfloat162float(Q.y);
        float l0 = __bfloat162float(L.x), l1 = __bfloat162float(L.y);
        float k0 = 1.f - l0, k1 = 1.f - l1;
        S00 = l0 * S00 + k0 * v0; S01 = l0 * S01 + k0 * v1;
        S10 = l1 * S10 + k1 * v0; S11 = l1 * S11 + k1 * v1;
        float o0 = q0 * S00 + q1 * S10;
        float o1 = q0 * S01 + q1 * S11;
        size_t ob = ((size_t)n * 257 + t) * 768 + h * 2;
        o[ob]     = __float2bfloat16(o0);
        o[ob + 1] = __float2bfloat16(o1);
    }
}

// ---------------------------------------------------------------- final: rmsnorm + layernorm + head GEMM (tiny)
__global__ __launch_bounds__(256) void head_kernel(const float* __restrict__ x, const float* __restrict__ g,
                                                   const float* __restrict__ be, const float* __restrict__ hw,
                                                   const float* __restrict__ hb, float* __restrict__ out) {
    int b = blockIdx.x;
    const float* xr = x + (size_t)b * 257 * 768;
    __shared__ float z[768];
    __shared__ float sbuf[8];
    float v[3];
    float ss = 0.f, d0 = 0.f;
    #pragma unroll
    for (int i = 0; i < 3; ++i) { v[i] = xr[threadIdx.x + i * 256]; ss += v[i] * v[i]; }
    block_reduce2(ss, d0, sbuf);
    float rs = rsqrtf(ss * (1.f / 768.f) + 1e-6f);
    float s = 0.f, s2 = 0.f;
    #pragma unroll
    for (int i = 0; i < 3; ++i) { float y = v[i] * rs; s += y; s2 += y * y; }
    block_reduce2(s, s2, sbuf);
    float mean = s * (1.f / 768.f);
    float var  = s2 * (1.f / 768.f) - mean * mean;
    float inv  = rsqrtf(var + 1e-5f);
    #pragma unroll
    for (int i = 0; i < 3; ++i) {
        int d = threadIdx.x + i * 256;
        z[d] = (v[i] * rs - mean) * inv * g[d] + be[d];
    }
    __syncthreads();
    int j = blockIdx.y * 256 + threadIdx.x;
    if (j < 1000) {
        float acc = hb[j];
        for (int d = 0; d < 768; ++d) acc += z[d] * hw[d * 1000 + j];
        out[b * 1000 + j] = acc;
    }
}

// ---------------------------------------------------------------- bf16 MFMA GEMM: C[M,N] = A[M,K] @ Bt[N,K]^T
// 128xNT tile (NT=128|64), BK=32, 4 waves (2x2), 4xNF 16x16x32 frags/wave.
// Register-prefetch pipeline, all indices compile-time.
// __launch_bounds__(256, 2): min 2 waves/EU -> 256-VGPR cap. Without it the compiler
// targets ~128 VGPRs (4 waves/EU heuristic) and spills the pipeline Stage structs to
// scratch — r3/r4 showed this as ~320 MB/dispatch of HBM WRITE (spill-store evictions).
// Per iter: gload tile k+2 -> regs (no wait), ds_write tile k+1 regs->LDS (vmcnt wait
// lands here, one full compute+barrier after issue), ds_read frags + MFMA tile k,
// ONE barrier draining only LDS ops.  K-loop unrolled x2 so stage/buffer parity is
// static (nk even at every call site).
// LDS XOR-swizzled (16B chunk ^= (row>>1)&3): 0 bank conflicts (measured r3).
// Split-K via blockIdx.z; linear epilogues accumulate with fp32 atomicAdd.
// EPI: 0=patch-embed partial (+= into pre-initialized x rows, row remap)
//      1=hgru feat (gelu/gelu/lambda) -> bf16  2=residual partial (+=)
//      3=bias+gelu->bf16  4=bias+residual partial (+=)
template<int EPI, int SPLITK, int NT>
__global__ __launch_bounds__(256, 2) void gemm_bt(
        const __hip_bfloat16* __restrict__ A, const __hip_bfloat16* __restrict__ Bt,
        int N, int Ktot, int Mvalid,
        float* __restrict__ outf, __hip_bfloat16* __restrict__ outb,
        const float* __restrict__ bias, const float* __restrict__ aux) {
    constexpr int NF = NT / 32;           // n-frags per wave
    constexpr int BJ = NT / 64;           // B staging loads per thread (1 or 2)
    __shared__ alignas(16) __hip_bfloat16 Als[2][128 * 32];
    __shared__ alignas(16) __hip_bfloat16 Bls[2][NT * 32];
    const int tid  = threadIdx.x;
    const int lane = tid & 63;
    const int wv   = tid >> 6;
    const int m0 = blockIdx.y * 128;
    const int n0 = blockIdx.x * NT;
    const int kLen  = Ktot / SPLITK;
    const int kBase = blockIdx.z * kLen;
    const int wm = wv & 1, wn = wv >> 1;
    const int fr = lane & 15;
    const int fq = lane >> 4;
    const int sr = tid >> 2;              // staging row 0..63 (+64)
    const int sc = tid & 3;               // staging 16B chunk 0..3

    floatx4 acc[4][NF];
    #pragma unroll
    for (int mi = 0; mi < 4; ++mi)
        #pragma unroll
        for (int ni = 0; ni < NF; ++ni)
            acc[mi][ni] = (floatx4){0.f, 0.f, 0.f, 0.f};

    struct Stage { int4 a0, a1, b0, b1; };
    Stage s0, s1;

    auto gload = [&](int kt, Stage& st) {
        st.a0 = *(const int4*)(A + (size_t)(m0 + sr) * Ktot + kBase + kt + sc * 8);
        st.a1 = *(const int4*)(A + (size_t)(m0 + sr + 64) * Ktot + kBase + kt + sc * 8);
        st.b0 = *(const int4*)(Bt + (size_t)(n0 + sr) * Ktot + kBase + kt + sc * 8);
        if (BJ > 1)
            st.b1 = *(const int4*)(Bt + (size_t)(n0 + sr + 64) * Ktot + kBase + kt + sc * 8);
    };
    auto swz = [&](int row, int chunk) -> int {   // byte offset inside a tile
        return row * 64 + ((chunk ^ ((row >> 1) & 3)) * 16);
    };
    auto swrite = [&](int buf, const Stage& st) {
        *(int4*)((char*)&Als[buf][0] + swz(sr, sc))      = st.a0;
        *(int4*)((char*)&Als[buf][0] + swz(sr + 64, sc)) = st.a1;
        *(int4*)((char*)&Bls[buf][0] + swz(sr, sc))      = st.b0;
        if (BJ > 1)
            *(int4*)((char*)&Bls[buf][0] + swz(sr + 64, sc)) = st.b1;
    };
    auto compute = [&](int buf) {
        bf16x8 af[4], bfv[NF];
        #pragma unroll
        for (int mi = 0; mi < 4; ++mi)
            af[mi] = *(const bf16x8*)((const char*)&Als[buf][0] + swz(wm * 64 + mi * 16 + fr, fq));
        #pragma unroll
        for (int ni = 0; ni < NF; ++ni)
            bfv[ni] = *(const bf16x8*)((const char*)&Bls[buf][0] + swz(wn * (NT / 2) + ni * 16 + fr, fq));
        #pragma unroll
        for (int mi = 0; mi < 4; ++mi)
            #pragma unroll
            for (int ni = 0; ni < NF; ++ni)
                acc[mi][ni] = __builtin_amdgcn_mfma_f32_16x16x32_bf16(af[mi], bfv[ni], acc[mi][ni], 0, 0, 0);
    };

    const int nk = kLen / 32;             // even at every call site
    gload(0, s0);
    gload(32, s1);
    swrite(0, s0);
    __syncthreads();

    for (int i = 0; i < nk; i += 2) {
        // even iter: compute buf0
        if (i + 2 < nk) gload((i + 2) * 32, s0);
        swrite(1, s1);                    // tile i+1 -> buf1 (prev buf1 reads done at last barrier)
        compute(0);
        __syncthreads();
        // odd iter: compute buf1
        if (i + 3 < nk) gload((i + 3) * 32, s1);
        if (i + 2 < nk) swrite(0, s0);    // tile i+2 -> buf0
        compute(1);
        if (i + 2 < nk) __syncthreads();
    }

    // C/D layout: col = lane&15, row = (lane>>4)*4 + reg  [m89/m91-verified]
    const int cr0 = wm * 64 + fq * 4;
    const int cc0 = wn * (NT / 2) + fr;
    #pragma unroll
    for (int mi = 0; mi < 4; ++mi) {
        #pragma unroll
        for (int r = 0; r < 4; ++r) {
            int gm = m0 + cr0 + mi * 16 + r;
            if (gm >= Mvalid) continue;
            #pragma unroll
            for (int ni = 0; ni < NF; ++ni) {
                int gn = n0 + cc0 + ni * 16;
                float v = acc[mi][ni][r];
                if (EPI == 0) {
                    int b = gm >> 8, p = gm & 255;
                    size_t orow = (size_t)b * 257 + 1 + p;
                    atomicAdd(&outf[orow * 768 + gn], v);
                } else if (EPI == 1) {
                    float res;
                    if (gn < 1536) {
                        res = gelu_f(v);
                    } else {
                        float l = aux[gn - 1536];
                        res = l + (1.f - l) / (1.f + expf(-v));
                    }
                    outb[(size_t)gm * N + gn] = __float2bfloat16(res);
                } else if (EPI == 2) {
                    if (SPLITK > 1) atomicAdd(&outf[(size_t)gm * N + gn], v);
                    else            outf[(size_t)gm * N + gn] += v;
                } else if (EPI == 3) {
                    outb[(size_t)gm * N + gn] = __float2bfloat16(gelu_f(v + bias[gn]));
                } else if (EPI == 4) {
                    float add = v + (blockIdx.z == 0 ? bias[gn] : 0.f);
                    if (SPLITK > 1) atomicAdd(&outf[(size_t)gm * N + gn], add);
                    else            outf[(size_t)gm * N + gn] += add;
                }
            }
        }
    }
}

// ----------------------------------------------------------------
extern "C" void kernel_launch(void* const* d_in, const int* in_sizes, int n_in,
                              void* d_out, int out_size, void* d_ws, size_t ws_size,
                              hipStream_t stream) {
    const float* img        = (const float*)d_in[0];
    const float* spt_ln_g   = (const float*)d_in[1];
    const float* spt_ln_b   = (const float*)d_in[2];
    const float* spt_w      = (const float*)d_in[3];
    const float* spt_b      = (const float*)d_in[4];
    const float* pos_emb    = (const float*)d_in[5];
    const float* cls_token  = (const float*)d_in[6];
    const float* lower_bnds = (const float*)d_in[7];
    const float* in_proj_w  = (const float*)d_in[8];
    const float* out_proj_w = (const float*)d_in[9];
    const float* ff_w1      = (const float*)d_in[10];
    const float* ff_b1      = (const float*)d_in[11];
    const float* ff_w2      = (const float*)d_in[12];
    const float* ff_b2      = (const float*)d_in[13];
    const float* head_ln_g  = (const float*)d_in[14];
    const float* head_ln_b  = (const float*)d_in[15];
    const float* head_w     = (const float*)d_in[16];
    const float* head_b     = (const float*)d_in[17];
    float* out = (float*)d_out;

    // ---- workspace bump allocator (256B aligned). Total ~120 MB.
    char* wp = (char*)d_ws;
    auto alloc = [&](size_t bytes) -> void* {
        void* p = (void*)wp;
        wp += (bytes + 255) & ~(size_t)255;
        return p;
    };
    float*          lbbuf   = (float*)         alloc(8 * 768 * 4);
    __hip_bfloat16* patches = (__hip_bfloat16*)alloc((size_t)4096 * 3840 * 2);
    __hip_bfloat16* spt_wt  = (__hip_bfloat16*)alloc((size_t)768 * 3840 * 2);
    float*          xbuf    = (float*)         alloc((size_t)4112 * 768 * 4);
    __hip_bfloat16* normbuf = (__hip_bfloat16*)alloc((size_t)4224 * 768 * 2);   // padded M
    __hip_bfloat16* featbuf = (__hip_bfloat16*)alloc((size_t)4112 * 2304 * 2);  // bf16
    __hip_bfloat16* obuf    = (__hip_bfloat16*)alloc((size_t)4224 * 768 * 2);   // padded M
    __hip_bfloat16* midbuf  = (__hip_bfloat16*)alloc((size_t)4224 * 3072 * 2);  // padded M
    __hip_bfloat16* w_in_t  = (__hip_bfloat16*)alloc((size_t)2304 * 768 * 2);
    __hip_bfloat16* w_out_t = (__hip_bfloat16*)alloc((size_t)768 * 768 * 2);
    __hip_bfloat16* w1_t    = (__hip_bfloat16*)alloc((size_t)3072 * 768 * 2);
    __hip_bfloat16* w2_t    = (__hip_bfloat16*)alloc((size_t)768 * 3072 * 2);
    (void)in_sizes; (void)n_in; (void)out_size; (void)ws_size;

    // ---- prologue
    compute_lb<<<3, 256, 0, stream>>>(lower_bnds, lbbuf);
    init_tokens<<<(16 * 257 * 768 + 255) / 256, 256, 0, stream>>>(cls_token, pos_emb, spt_b, xbuf);
    patch_ln<<<4096, 256, 0, stream>>>(img, spt_ln_g, spt_ln_b, patches);
    transpose_cast<<<dim3(3840 / 32, 768 / 32), 256, 0, stream>>>(spt_w, spt_wt, 3840, 768);
    // x rows (b*257+1+p) += LN(patches) @ spt_w   (bias+pos already in xbuf), split-K=4, nk=30
    gemm_bt<0, 4, 128><<<dim3(6, 32, 4), 256, 0, stream>>>(patches, spt_wt, 768, 3840, 4096,
                                                           xbuf, nullptr, nullptr, nullptr);

    // ---- layers
    for (int i = 0; i < 8; ++i) {
        rmsnorm_kernel<<<4112, 256, 0, stream>>>(xbuf, normbuf);
        transpose_cast<<<dim3(24, 72), 256, 0, stream>>>(in_proj_w + (size_t)i * 768 * 2304, w_in_t, 768, 2304);
        gemm_bt<1, 1, 128><<<dim3(18, 33, 1), 256, 0, stream>>>(normbuf, w_in_t, 2304, 768, 4112,
                                                                nullptr, featbuf, nullptr, lbbuf + i * 768);  // nk=24
        hgru_scan<<<386, 256, 0, stream>>>((const __hip_bfloat162*)featbuf, obuf);
        transpose_cast<<<dim3(24, 24), 256, 0, stream>>>(out_proj_w + (size_t)i * 768 * 768, w_out_t, 768, 768);
        gemm_bt<2, 2, 64><<<dim3(12, 33, 2), 256, 0, stream>>>(obuf, w_out_t, 768, 768, 4112,
                                                               xbuf, nullptr, nullptr, nullptr);             // nk=12
        rmsnorm_kernel<<<4112, 256, 0, stream>>>(xbuf, normbuf);
        transpose_cast<<<dim3(24, 96), 256, 0, stream>>>(ff_w1 + (size_t)i * 768 * 3072, w1_t, 768, 3072);
        gemm_bt<3, 1, 128><<<dim3(24, 33, 1), 256, 0, stream>>>(normbuf, w1_t, 3072, 768, 4112,
                                                                nullptr, midbuf, ff_b1 + i * 3072, nullptr); // nk=24
        transpose_cast<<<dim3(96, 24), 256, 0, stream>>>(ff_w2 + (size_t)i * 3072 * 768, w2_t, 3072, 768);
        gemm_bt<4, 4, 128><<<dim3(6, 33, 4), 256, 0, stream>>>(midbuf, w2_t, 768, 3072, 4112,
                                                               xbuf, nullptr, ff_b2 + i * 768, nullptr);     // nk=24
    }

    // ---- head
    head_kernel<<<dim3(16, 4), 256, 0, stream>>>(xbuf, head_ln_g, head_ln_b, head_w, head_b, out);
}

// Round 6
// 2270.792 us; speedup vs baseline: 1.9743x; 1.9153x over previous
//
#include <hip/hip_runtime.h>
#include <hip/hip_bf16.h>

typedef __bf16 bf16x8 __attribute__((ext_vector_type(8)));
typedef float floatx4 __attribute__((ext_vector_type(4)));

#define DEV __device__ __forceinline__

DEV float gelu_f(float x) {
    return 0.5f * x * (1.0f + erff(x * 0.70710678118654752f));
}

DEV void block_reduce2(float& a, float& b, float* s) {
    #pragma unroll
    for (int o = 32; o > 0; o >>= 1) {
        a += __shfl_down(a, o, 64);
        b += __shfl_down(b, o, 64);
    }
    __syncthreads();
    int wv = threadIdx.x >> 6;
    if ((threadIdx.x & 63) == 0) { s[wv * 2] = a; s[wv * 2 + 1] = b; }
    __syncthreads();
    int nw = blockDim.x >> 6;
    float ra = 0.f, rb = 0.f;
    for (int i = 0; i < nw; ++i) { ra += s[i * 2]; rb += s[i * 2 + 1]; }
    a = ra; b = rb;
}

// ---------------------------------------------------------------- lb: softmax over depth, cumsum, minus first
__global__ __launch_bounds__(256) void compute_lb(const float* __restrict__ lbin, float* __restrict__ lbout) {
    int d = blockIdx.x * 256 + threadIdx.x;
    if (d >= 768) return;
    float v[8];
    float mx = -1e30f;
    #pragma unroll
    for (int i = 0; i < 8; ++i) { v[i] = lbin[i * 768 + d]; mx = fmaxf(mx, v[i]); }
    float s = 0.f;
    #pragma unroll
    for (int i = 0; i < 8; ++i) { v[i] = expf(v[i] - mx); s += v[i]; }
    float inv = 1.f / s;
    float first = v[0] * inv;
    float cum = 0.f;
    #pragma unroll
    for (int i = 0; i < 8; ++i) { cum += v[i] * inv; lbout[i * 768 + d] = cum - first; }
}

// ---------------------------------------------------------------- x init: cls row = cls+pos[0]; token rows = spt_b+pos[1+p]
__global__ __launch_bounds__(256) void init_tokens(const float* __restrict__ cls, const float* __restrict__ pos,
                                                   const float* __restrict__ bias, float* __restrict__ x) {
    int i = blockIdx.x * 256 + threadIdx.x;       // 16*257*768 = 3157248
    if (i >= 16 * 257 * 768) return;
    int d = i % 768;
    int row = i / 768;                             // b*257 + t
    int t = row % 257;
    float v;
    if (t == 0) v = cls[d] + pos[d];
    else        v = bias[d] + pos[(size_t)t * 768 + d];
    x[(size_t)row * 768 + d] = v;
}

// ---------------------------------------------------------------- patch gather + layernorm -> bf16 [4096 x 3840]
__global__ __launch_bounds__(256) void patch_ln(const float* __restrict__ img, const float* __restrict__ g,
                                                const float* __restrict__ bt, __hip_bfloat16* __restrict__ out) {
    int pm = blockIdx.x;              // 0..4095   = b*256 + (ph*16+pw)
    int b = pm >> 8, pp = pm & 255;
    int ph = pp >> 4, pw = pp & 15;
    __shared__ float pv[3840];
    __shared__ float sbuf[8];
    float s = 0.f, ss = 0.f;
    #pragma unroll
    for (int i = 0; i < 15; ++i) {
        int f = threadIdx.x + i * 256;
        int pi = f / 15, cc = f % 15;
        int ip = pi >> 4, jp = pi & 15;
        int g5 = cc / 3, ch = cc % 3;
        int sh = (g5 == 3) - (g5 == 4);       // groups: 0:(0,0) 1:(0,1) 2:(0,-1) 3:(1,0) 4:(-1,0)
        int sw = (g5 == 1) - (g5 == 2);
        int y = ph * 16 + ip - sh;
        int x = pw * 16 + jp - sw;
        float val = 0.f;
        if ((unsigned)y < 256u && (unsigned)x < 256u)
            val = img[(((size_t)b * 3 + ch) * 256 + y) * 256 + x];
        pv[f] = val; s += val; ss += val * val;
    }
    block_reduce2(s, ss, sbuf);
    float mean = s * (1.f / 3840.f);
    float var  = ss * (1.f / 3840.f) - mean * mean;
    float inv  = rsqrtf(var + 1e-5f);
    #pragma unroll
    for (int i = 0; i < 15; ++i) {
        int f = threadIdx.x + i * 256;
        out[(size_t)pm * 3840 + f] = __float2bfloat16((pv[f] - mean) * inv * g[f] + bt[f]);
    }
}

// ---------------------------------------------------------------- fp32 [K,N] -> bf16 [N,K] tiled transpose-cast
__global__ __launch_bounds__(256) void transpose_cast(const float* __restrict__ W, __hip_bfloat16* __restrict__ Wt,
                                                      int K, int N) {
    __shared__ float tile[32][33];
    int k0 = blockIdx.x * 32, n0 = blockIdx.y * 32;
    int tx = threadIdx.x & 31, ty = threadIdx.x >> 5;   // ty 0..7
    #pragma unroll
    for (int i = 0; i < 4; ++i) {
        int k = ty + i * 8;
        tile[k][tx] = W[(size_t)(k0 + k) * N + n0 + tx];
    }
    __syncthreads();
    #pragma unroll
    for (int i = 0; i < 4; ++i) {
        int n = ty + i * 8;
        Wt[(size_t)(n0 + n) * K + k0 + tx] = __float2bfloat16(tile[tx][n]);
    }
}

// ---------------------------------------------------------------- rmsnorm fp32 -> bf16, row = 768
__global__ __launch_bounds__(256) void rmsnorm_kernel(const float* __restrict__ x, __hip_bfloat16* __restrict__ out) {
    int row = blockIdx.x;
    const float* xr = x + (size_t)row * 768;
    __shared__ float sbuf[8];
    float v[3];
    float ss = 0.f, d0 = 0.f;
    #pragma unroll
    for (int i = 0; i < 3; ++i) { v[i] = xr[threadIdx.x + i * 256]; ss += v[i] * v[i]; }
    block_reduce2(ss, d0, sbuf);
    float scale = rsqrtf(ss * (1.f / 768.f) + 1e-6f);
    #pragma unroll
    for (int i = 0; i < 3; ++i)
        out[(size_t)row * 768 + threadIdx.x + i * 256] = __float2bfloat16(v[i] * scale);
}

// ---------------------------------------------------------------- hgru2 scan over BATCH axis (N=16), per (t,h), bf16 feat
__global__ __launch_bounds__(256) void hgru_scan(const __hip_bfloat162* __restrict__ feat,
                                                 __hip_bfloat16* __restrict__ o) {
    int idx = blockIdx.x * 256 + threadIdx.x;
    if (idx >= 257 * 384) return;
    int t = idx / 384, h = idx % 384;
    float S00 = 0.f, S01 = 0.f, S10 = 0.f, S11 = 0.f;
    for (int n = 0; n < 16; ++n) {
        size_t b2 = ((size_t)n * 257 + t) * 1152;    // row base in bf16x2 units
        __hip_bfloat162 V = feat[b2 + h];
        __hip_bfloat162 Q = feat[b2 + 384 + h];
        __hip_bfloat162 L = feat[b2 + 768 + h];
        float v0 = __bfloat162float(V.x), v1 = __bfloat162float(V.y);
        float q0 = __bfloat162float(Q.x), q1 = __bfloat162float(Q.y);
        float l0 = __bfloat162float(L.x), l1 = __bfloat162float(L.y);
        float k0 = 1.f - l0, k1 = 1.f - l1;
        S00 = l0 * S00 + k0 * v0; S01 = l0 * S01 + k0 * v1;
        S10 = l1 * S10 + k1 * v0; S11 = l1 * S11 + k1 * v1;
        float o0 = q0 * S00 + q1 * S10;
        float o1 = q0 * S01 + q1 * S11;
        size_t ob = ((size_t)n * 257 + t) * 768 + h * 2;
        o[ob]     = __float2bfloat16(o0);
        o[ob + 1] = __float2bfloat16(o1);
    }
}

// ---------------------------------------------------------------- final: rmsnorm + layernorm + head GEMM (tiny)
__global__ __launch_bounds__(256) void head_kernel(const float* __restrict__ x, const float* __restrict__ g,
                                                   const float* __restrict__ be, const float* __restrict__ hw,
                                                   const float* __restrict__ hb, float* __restrict__ out) {
    int b = blockIdx.x;
    const float* xr = x + (size_t)b * 257 * 768;
    __shared__ float z[768];
    __shared__ float sbuf[8];
    float v[3];
    float ss = 0.f, d0 = 0.f;
    #pragma unroll
    for (int i = 0; i < 3; ++i) { v[i] = xr[threadIdx.x + i * 256]; ss += v[i] * v[i]; }
    block_reduce2(ss, d0, sbuf);
    float rs = rsqrtf(ss * (1.f / 768.f) + 1e-6f);
    float s = 0.f, s2 = 0.f;
    #pragma unroll
    for (int i = 0; i < 3; ++i) { float y = v[i] * rs; s += y; s2 += y * y; }
    block_reduce2(s, s2, sbuf);
    float mean = s * (1.f / 768.f);
    float var  = s2 * (1.f / 768.f) - mean * mean;
    float inv  = rsqrtf(var + 1e-5f);
    #pragma unroll
    for (int i = 0; i < 3; ++i) {
        int d = threadIdx.x + i * 256;
        z[d] = (v[i] * rs - mean) * inv * g[d] + be[d];
    }
    __syncthreads();
    int j = blockIdx.y * 256 + threadIdx.x;
    if (j < 1000) {
        float acc = hb[j];
        for (int d = 0; d < 768; ++d) acc += z[d] * hw[d * 1000 + j];
        out[b * 1000 + j] = acc;
    }
}

// ---------------------------------------------------------------- bf16 MFMA GEMM: C[M,N] = A[M,K] @ Bt[N,K]^T
// 128xNT tile (NT=64|128), BK=32, 4 waves (2x2), 4xNF 16x16x32 frags/wave.
// r2-proven inner loop: global_load_lds width-16 direct-to-LDS staging, double-buffered,
// stage(k+1) issued before MFMA(k), one barrier per iter. No manual reg pipeline —
// rounds 3-5 proved the compiler spills it to scratch (~330 MB/dispatch HBM writes).
// The barrier's vmcnt(0) drain is instead hidden by TLP: NT=64 (24 KB LDS) + split-K
// put every big GEMM at ~5-6 blocks/CU so other blocks compute through the drain (m114).
// Split-K via blockIdx.z; linear epilogues accumulate with fp32 atomicAdd.
// EPI: 0=patch-embed partial (+= into pre-initialized x rows, row remap)
//      1=hgru feat (gelu/gelu/lambda) -> bf16  2=residual partial (+=)
//      3=bias+gelu->bf16  4=bias+residual partial (+=)
template<int EPI, int SPLITK, int NT>
__global__ __launch_bounds__(256) void gemm_bt(
        const __hip_bfloat16* __restrict__ A, const __hip_bfloat16* __restrict__ Bt,
        int N, int Ktot, int Mvalid,
        float* __restrict__ outf, __hip_bfloat16* __restrict__ outb,
        const float* __restrict__ bias, const float* __restrict__ aux) {
    constexpr int NF = NT / 32;           // n-frags per wave (2 or 4)
    constexpr int BJ = NT / 64;           // B staging chunks per wave (1 or 2)
    __shared__ alignas(16) __hip_bfloat16 Als[2][128 * 32];
    __shared__ alignas(16) __hip_bfloat16 Bls[2][NT * 32];
    const int tid  = threadIdx.x;
    const int lane = tid & 63;
    const int wv   = tid >> 6;
    const int m0 = blockIdx.y * 128;
    const int n0 = blockIdx.x * NT;
    const int kLen  = Ktot / SPLITK;
    const int kBase = blockIdx.z * kLen;
    const int wm = wv & 1, wn = wv >> 1;
    const int fr = lane & 15;
    const int fq = lane >> 4;
    const int srow = lane >> 2;           // 0..15 within a 16-row chunk
    const int scol = (lane & 3) * 8;      // bf16 elem offset within 32-wide row

    floatx4 acc[4][NF];
    #pragma unroll
    for (int mi = 0; mi < 4; ++mi)
        #pragma unroll
        for (int ni = 0; ni < NF; ++ni)
            acc[mi][ni] = (floatx4){0.f, 0.f, 0.f, 0.f};

    auto stage = [&](int kt, int buf) {
        #pragma unroll
        for (int j = 0; j < 2; ++j) {                 // A: 128 rows = 8 chunks of 16
            int cc = wv * 2 + j;
            int r  = cc * 16 + srow;
            const __hip_bfloat16* ga = A + (size_t)(m0 + r) * Ktot + kBase + kt + scol;
            __builtin_amdgcn_global_load_lds((const __attribute__((address_space(1))) void*)ga,
                                             (__attribute__((address_space(3))) void*)(&Als[buf][cc * 512]), 16, 0, 0);
        }
        #pragma unroll
        for (int j = 0; j < BJ; ++j) {                // B: NT rows = 4*BJ chunks of 16
            int cc = wv * BJ + j;
            int r  = cc * 16 + srow;
            const __hip_bfloat16* gb = Bt + (size_t)(n0 + r) * Ktot + kBase + kt + scol;
            __builtin_amdgcn_global_load_lds((const __attribute__((address_space(1))) void*)gb,
                                             (__attribute__((address_space(3))) void*)(&Bls[buf][cc * 512]), 16, 0, 0);
        }
    };

    const int nk = kLen / 32;
    stage(0, 0);
    __syncthreads();

    for (int i = 0; i < nk; ++i) {
        const int cur = i & 1;
        bf16x8 af[4], bfv[NF];
        #pragma unroll
        for (int mi = 0; mi < 4; ++mi)
            af[mi] = *(const bf16x8*)((const void*)&Als[cur][(wm * 64 + mi * 16 + fr) * 32 + fq * 8]);
        #pragma unroll
        for (int ni = 0; ni < NF; ++ni)
            bfv[ni] = *(const bf16x8*)((const void*)&Bls[cur][(wn * (NT / 2) + ni * 16 + fr) * 32 + fq * 8]);
        if (i + 1 < nk) stage((i + 1) * 32, cur ^ 1);
        #pragma unroll
        for (int mi = 0; mi < 4; ++mi)
            #pragma unroll
            for (int ni = 0; ni < NF; ++ni)
                acc[mi][ni] = __builtin_amdgcn_mfma_f32_16x16x32_bf16(af[mi], bfv[ni], acc[mi][ni], 0, 0, 0);
        __syncthreads();
    }

    // C/D layout: col = lane&15, row = (lane>>4)*4 + reg  [m89/m91-verified]
    const int cr0 = wm * 64 + fq * 4;
    const int cc0 = wn * (NT / 2) + fr;
    #pragma unroll
    for (int mi = 0; mi < 4; ++mi) {
        #pragma unroll
        for (int r = 0; r < 4; ++r) {
            int gm = m0 + cr0 + mi * 16 + r;
            if (gm >= Mvalid) continue;
            #pragma unroll
            for (int ni = 0; ni < NF; ++ni) {
                int gn = n0 + cc0 + ni * 16;
                float v = acc[mi][ni][r];
                if (EPI == 0) {
                    int b = gm >> 8, p = gm & 255;
                    size_t orow = (size_t)b * 257 + 1 + p;
                    atomicAdd(&outf[orow * 768 + gn], v);
                } else if (EPI == 1) {
                    float res;
                    if (gn < 1536) {
                        res = gelu_f(v);
                    } else {
                        float l = aux[gn - 1536];
                        res = l + (1.f - l) / (1.f + expf(-v));
                    }
                    outb[(size_t)gm * N + gn] = __float2bfloat16(res);
                } else if (EPI == 2) {
                    if (SPLITK > 1) atomicAdd(&outf[(size_t)gm * N + gn], v);
                    else            outf[(size_t)gm * N + gn] += v;
                } else if (EPI == 3) {
                    outb[(size_t)gm * N + gn] = __float2bfloat16(gelu_f(v + bias[gn]));
                } else if (EPI == 4) {
                    float add = v + (blockIdx.z == 0 ? bias[gn] : 0.f);
                    if (SPLITK > 1) atomicAdd(&outf[(size_t)gm * N + gn], add);
                    else            outf[(size_t)gm * N + gn] += add;
                }
            }
        }
    }
}

// ----------------------------------------------------------------
extern "C" void kernel_launch(void* const* d_in, const int* in_sizes, int n_in,
                              void* d_out, int out_size, void* d_ws, size_t ws_size,
                              hipStream_t stream) {
    const float* img        = (const float*)d_in[0];
    const float* spt_ln_g   = (const float*)d_in[1];
    const float* spt_ln_b   = (const float*)d_in[2];
    const float* spt_w      = (const float*)d_in[3];
    const float* spt_b      = (const float*)d_in[4];
    const float* pos_emb    = (const float*)d_in[5];
    const float* cls_token  = (const float*)d_in[6];
    const float* lower_bnds = (const float*)d_in[7];
    const float* in_proj_w  = (const float*)d_in[8];
    const float* out_proj_w = (const float*)d_in[9];
    const float* ff_w1      = (const float*)d_in[10];
    const float* ff_b1      = (const float*)d_in[11];
    const float* ff_w2      = (const float*)d_in[12];
    const float* ff_b2      = (const float*)d_in[13];
    const float* head_ln_g  = (const float*)d_in[14];
    const float* head_ln_b  = (const float*)d_in[15];
    const float* head_w     = (const float*)d_in[16];
    const float* head_b     = (const float*)d_in[17];
    float* out = (float*)d_out;

    // ---- workspace bump allocator (256B aligned). Total ~120 MB.
    char* wp = (char*)d_ws;
    auto alloc = [&](size_t bytes) -> void* {
        void* p = (void*)wp;
        wp += (bytes + 255) & ~(size_t)255;
        return p;
    };
    float*          lbbuf   = (float*)         alloc(8 * 768 * 4);
    __hip_bfloat16* patches = (__hip_bfloat16*)alloc((size_t)4096 * 3840 * 2);
    __hip_bfloat16* spt_wt  = (__hip_bfloat16*)alloc((size_t)768 * 3840 * 2);
    float*          xbuf    = (float*)         alloc((size_t)4112 * 768 * 4);
    __hip_bfloat16* normbuf = (__hip_bfloat16*)alloc((size_t)4224 * 768 * 2);   // padded M
    __hip_bfloat16* featbuf = (__hip_bfloat16*)alloc((size_t)4112 * 2304 * 2);  // bf16
    __hip_bfloat16* obuf    = (__hip_bfloat16*)alloc((size_t)4224 * 768 * 2);   // padded M
    __hip_bfloat16* midbuf  = (__hip_bfloat16*)alloc((size_t)4224 * 3072 * 2);  // padded M
    __hip_bfloat16* w_in_t  = (__hip_bfloat16*)alloc((size_t)2304 * 768 * 2);
    __hip_bfloat16* w_out_t = (__hip_bfloat16*)alloc((size_t)768 * 768 * 2);
    __hip_bfloat16* w1_t    = (__hip_bfloat16*)alloc((size_t)3072 * 768 * 2);
    __hip_bfloat16* w2_t    = (__hip_bfloat16*)alloc((size_t)768 * 3072 * 2);
    (void)in_sizes; (void)n_in; (void)out_size; (void)ws_size;

    // ---- prologue
    compute_lb<<<3, 256, 0, stream>>>(lower_bnds, lbbuf);
    init_tokens<<<(16 * 257 * 768 + 255) / 256, 256, 0, stream>>>(cls_token, pos_emb, spt_b, xbuf);
    patch_ln<<<4096, 256, 0, stream>>>(img, spt_ln_g, spt_ln_b, patches);
    transpose_cast<<<dim3(3840 / 32, 768 / 32), 256, 0, stream>>>(spt_w, spt_wt, 3840, 768);
    // x rows (b*257+1+p) += LN(patches) @ spt_w  (bias+pos already in xbuf). split4, nk=30, 1536 blocks
    gemm_bt<0, 4, 64><<<dim3(12, 32, 4), 256, 0, stream>>>(patches, spt_wt, 768, 3840, 4096,
                                                           xbuf, nullptr, nullptr, nullptr);

    // ---- layers
    for (int i = 0; i < 8; ++i) {
        rmsnorm_kernel<<<4112, 256, 0, stream>>>(xbuf, normbuf);
        transpose_cast<<<dim3(24, 72), 256, 0, stream>>>(in_proj_w + (size_t)i * 768 * 2304, w_in_t, 768, 2304);
        // nk=24, 1188 blocks
        gemm_bt<1, 1, 64><<<dim3(36, 33, 1), 256, 0, stream>>>(normbuf, w_in_t, 2304, 768, 4112,
                                                               nullptr, featbuf, nullptr, lbbuf + i * 768);
        hgru_scan<<<386, 256, 0, stream>>>((const __hip_bfloat162*)featbuf, obuf);
        transpose_cast<<<dim3(24, 24), 256, 0, stream>>>(out_proj_w + (size_t)i * 768 * 768, w_out_t, 768, 768);
        // nk=6, 1584 blocks
        gemm_bt<2, 4, 64><<<dim3(12, 33, 4), 256, 0, stream>>>(obuf, w_out_t, 768, 768, 4112,
                                                               xbuf, nullptr, nullptr, nullptr);
        rmsnorm_kernel<<<4112, 256, 0, stream>>>(xbuf, normbuf);
        transpose_cast<<<dim3(24, 96), 256, 0, stream>>>(ff_w1 + (size_t)i * 768 * 3072, w1_t, 768, 3072);
        // nk=24, 1584 blocks
        gemm_bt<3, 1, 64><<<dim3(48, 33, 1), 256, 0, stream>>>(normbuf, w1_t, 3072, 768, 4112,
                                                               nullptr, midbuf, ff_b1 + i * 3072, nullptr);
        transpose_cast<<<dim3(96, 24), 256, 0, stream>>>(ff_w2 + (size_t)i * 3072 * 768, w2_t, 3072, 768);
        // nk=24, 1584 blocks
        gemm_bt<4, 4, 64><<<dim3(12, 33, 4), 256, 0, stream>>>(midbuf, w2_t, 768, 3072, 4112,
                                                               xbuf, nullptr, ff_b2 + i * 768, nullptr);
    }

    // ---- head
    head_kernel<<<dim3(16, 4), 256, 0, stream>>>(xbuf, head_ln_g, head_ln_b, head_w, head_b, out);
}